// Round 8
// baseline (336.549 us; speedup 1.0000x reference)
//
#include <hip/hip_runtime.h>

#define NEG_SLOPE 0.2f
#define RSHIFT 6       // range width 64 dst nodes -> LDS-resident counting sort
#define RW     64
#define MAXNR  800     // supports N <= 51200
#define CHUNKP 8192    // edges per partition block

__device__ __forceinline__ ushort f2bf(float f) {
    union { float f; unsigned u; } c; c.f = f;
    unsigned u = c.u;
    return (ushort)((u + 0x7fffu + ((u >> 16) & 1u)) >> 16);   // RNE
}

// ---------------- mega: edge partition | scores | out[:, :128]=x + xbf=bf16(x)
__global__ __launch_bounds__(256) void mega_kernel(
    const float* __restrict__ x, const float* __restrict__ wu,
    const float* __restrict__ bu, const float* __restrict__ wv,
    const int* __restrict__ s0, const int* __restrict__ d0,
    const int* __restrict__ s1, const int* __restrict__ d1,
    float* __restrict__ out, ushort* __restrict__ xbf,
    float* __restrict__ su, float* __restrict__ sv,
    int* __restrict__ gcur, unsigned* __restrict__ pairs,
    int N, int E, int nr, int cap, int partBlocks, int scoreBlocks, int ppset)
{
    __shared__ float wlds[32 * 129];          // 16.5 KB; aliased by partition role
    int* smi = (int*)wlds;
    int tid = threadIdx.x;
    int bid = blockIdx.x;

    if (bid < partBlocks) {                   // ---- role C: partition edges
        int t = bid / ppset, c = bid % ppset;
        const int* ss = t ? s1 : s0;
        const int* dd = t ? d1 : d0;
        int beg = c * CHUNKP, end = min(E, beg + CHUNKP);
        int* lcnt = smi; int* gb = smi + MAXNR; int* lrun = smi + 2 * MAXNR;
        for (int i = tid; i < nr; i += 256) lcnt[i] = 0;
        __syncthreads();
        for (int e = beg + tid; e < end; e += 256)
            atomicAdd(&lcnt[dd[e] >> RSHIFT], 1);
        __syncthreads();
        for (int i = tid; i < nr; i += 256) {
            gb[i] = atomicAdd(&gcur[t * nr + i], lcnt[i]);
            lrun[i] = 0;
        }
        __syncthreads();
        unsigned* pt = pairs + (size_t)t * nr * cap;
        for (int e = beg + tid; e < end; e += 256) {
            int dst = dd[e], src = ss[e];
            int r = dst >> RSHIFT;
            int pos = atomicAdd(&lrun[r], 1);
            pt[(size_t)r * cap + gb[r] + pos] = ((unsigned)dst << 16) | (unsigned)src;
        }
        return;
    }
    if (bid < partBlocks + scoreBlocks) {     // ---- role B: scores, 4 nodes/thread
        for (int i = tid; i < 4096; i += 256) {
            int o = i >> 7, k = i & 127;
            wlds[o * 129 + k] = (o < 16) ? wu[i] : wv[i - 2048];
        }
        __syncthreads();
        int o = tid & 15, slot = tid >> 4;
        int n0 = (bid - partBlocks) * 64 + slot * 4;
        int na = min(n0,     N - 1), nb2 = min(n0 + 1, N - 1);
        int nc = min(n0 + 2, N - 1), nd = min(n0 + 3, N - 1);
        const float4* xa = (const float4*)(x + (size_t)na * 128);
        const float4* xb = (const float4*)(x + (size_t)nb2 * 128);
        const float4* xc = (const float4*)(x + (size_t)nc * 128);
        const float4* xd = (const float4*)(x + (size_t)nd * 128);
        const float* wur = wlds + o * 129;
        const float* wvr = wlds + (16 + o) * 129;
        float au0 = 0.f, au1 = 0.f, au2 = 0.f, au3 = 0.f;
        float av0 = 0.f, av1 = 0.f, av2 = 0.f, av3 = 0.f;
#pragma unroll
        for (int kk = 0; kk < 32; ++kk) {
            int k = kk * 4;
            float wu0 = wur[k], wu1 = wur[k + 1], wu2 = wur[k + 2], wu3 = wur[k + 3];
            float wv0 = wvr[k], wv1 = wvr[k + 1], wv2 = wvr[k + 2], wv3 = wvr[k + 3];
            float4 a = xa[kk], b = xb[kk], cc = xc[kk], dd4 = xd[kk];
            au0 = fmaf(a.x, wu0, au0);  av0 = fmaf(a.x, wv0, av0);
            au0 = fmaf(a.y, wu1, au0);  av0 = fmaf(a.y, wv1, av0);
            au0 = fmaf(a.z, wu2, au0);  av0 = fmaf(a.z, wv2, av0);
            au0 = fmaf(a.w, wu3, au0);  av0 = fmaf(a.w, wv3, av0);
            au1 = fmaf(b.x, wu0, au1);  av1 = fmaf(b.x, wv0, av1);
            au1 = fmaf(b.y, wu1, au1);  av1 = fmaf(b.y, wv1, av1);
            au1 = fmaf(b.z, wu2, au1);  av1 = fmaf(b.z, wv2, av1);
            au1 = fmaf(b.w, wu3, au1);  av1 = fmaf(b.w, wv3, av1);
            au2 = fmaf(cc.x, wu0, au2); av2 = fmaf(cc.x, wv0, av2);
            au2 = fmaf(cc.y, wu1, au2); av2 = fmaf(cc.y, wv1, av2);
            au2 = fmaf(cc.z, wu2, au2); av2 = fmaf(cc.z, wv2, av2);
            au2 = fmaf(cc.w, wu3, au2); av2 = fmaf(cc.w, wv3, av2);
            au3 = fmaf(dd4.x, wu0, au3); av3 = fmaf(dd4.x, wv0, av3);
            au3 = fmaf(dd4.y, wu1, au3); av3 = fmaf(dd4.y, wv1, av3);
            au3 = fmaf(dd4.z, wu2, au3); av3 = fmaf(dd4.z, wv2, av3);
            au3 = fmaf(dd4.w, wu3, au3); av3 = fmaf(dd4.w, wv3, av3);
        }
        float bo = bu[o];
        if (n0 < N)     { su[n0 * 16 + o]       = au0 + bo; sv[n0 * 16 + o]       = av0; }
        if (n0 + 1 < N) { su[(n0 + 1) * 16 + o] = au1 + bo; sv[(n0 + 1) * 16 + o] = av1; }
        if (n0 + 2 < N) { su[(n0 + 2) * 16 + o] = au2 + bo; sv[(n0 + 2) * 16 + o] = av2; }
        if (n0 + 3 < N) { su[(n0 + 3) * 16 + o] = au3 + bo; sv[(n0 + 3) * 16 + o] = av3; }
        return;
    }
    // ---- role A: copy + bf16 convert (2048 float4 per block)
    int base = (bid - partBlocks - scoreBlocks) * 2048 + tid;
#pragma unroll
    for (int j = 0; j < 8; ++j) {
        int i = base + j * 256;
        if (i < N * 32) {
            float4 v = ((const float4*)x)[i];
            int n = i >> 5, q = i & 31;
            ((float4*)out)[(size_t)n * 96 + q] = v;
            ushort4 b;
            b.x = f2bf(v.x); b.y = f2bf(v.y); b.z = f2bf(v.z); b.w = f2bf(v.w);
            *(ushort4*)(xbf + (size_t)i * 4) = b;
        }
    }
}

// ---------------- buildagg: per-(range,set) block. LDS counting-sort, then
// per-node single-pass softmax + quarter-wave gather-aggregate (4 edges/iter).
__global__ __launch_bounds__(256, 8) void buildagg_kernel(
    const ushort* __restrict__ xbf, const float* __restrict__ su,
    const float* __restrict__ sv, const int* __restrict__ gcur,
    const unsigned* __restrict__ pairs, float* __restrict__ out,
    int N, int E, int nr, int cap)
{
    __shared__ ushort srcs[1408];             // sorted src ids (cap <= 1344)
    __shared__ int offl[65];
    __shared__ int cursor[64];
    __shared__ __align__(16) float ev4[4][512];
    int r = blockIdx.x, t = blockIdx.y, tid = threadIdx.x;
    int m = gcur[t * nr + r];
    if (m > cap) m = cap;                     // safety (never expected)
    const unsigned* p = pairs + ((size_t)t * nr + r) * cap;

    if (tid < 64) cursor[tid] = 0;
    __syncthreads();
    for (int i = tid; i < m; i += 256)        // pass 1: histogram (local node id)
        atomicAdd(&cursor[(p[i] >> 16) & (RW - 1)], 1);
    __syncthreads();
    if (tid < 64) {                           // 64-wide shfl scan -> offsets
        int v = cursor[tid];
        int incl = v;
#pragma unroll
        for (int d = 1; d < 64; d <<= 1) {
            int o = __shfl(incl, tid - d);
            if (tid >= d) incl += o;
        }
        offl[tid + 1] = incl;
        if (tid == 0) offl[0] = 0;
        cursor[tid] = incl - v;               // exclusive -> scatter cursor
    }
    __syncthreads();
    for (int i = tid; i < m; i += 256) {      // pass 2: scatter into LDS bucket
        unsigned v = p[i];
        int pos = atomicAdd(&cursor[(v >> 16) & (RW - 1)], 1);
        srcs[pos] = (ushort)(v & 0xffffu);
    }
    __syncthreads();

    // ---- agg: wave w handles local nodes w, w+4, ...
    int wid = tid >> 6, lane = tid & 63;
    int h = lane & 7, e8 = lane >> 3;         // e-phase: 8 edges x 8 heads
    int qtr = lane >> 4, q16 = lane & 15;     // acc-phase: 4 edges, 8 floats/lane
    int j0 = q16 * 8;
    float* ev = ev4[wid];
    for (int ln = wid; ln < RW; ln += 4) {
        int n = (r << RSHIFT) + ln;
        if (n >= N) break;
        int beg = offl[ln], end = offl[ln + 1];
        float vh = sv[n * 16 + t * 8 + h];
        float a0 = 0.f, a1 = 0.f, a2 = 0.f, a3 = 0.f;
        float a4 = 0.f, a5 = 0.f, a6 = 0.f, a7 = 0.f;
        float l = 0.f;
        for (int cbeg = beg; cbeg < end; cbeg += 64) {
            int cnt = min(end - cbeg, 64);
            int gmax = (cnt + 7) >> 3;
            for (int g = 0; g < gmax; ++g) {  // e-phase
                int e = g * 8 + e8;
                bool valid = e < cnt;
                int srcv = srcs[cbeg + (valid ? e : 0)];
                float sc = su[srcv * 16 + t * 8 + h] + vh;
                sc = (sc >= 0.f) ? sc : NEG_SLOPE * sc;
                float ee = valid ? __expf(sc) : 0.f;
                l += ee;
                ev[e * 8 + h] = ee;
            }
            int quads = (cnt + 3) >> 2;       // acc-phase: 4 edges/iter
#pragma unroll 2
            for (int i4 = 0; i4 < quads; ++i4) {
                int eidx = i4 * 4 + qtr;      // < gmax*8, ev always written
                int srcv = srcs[cbeg + ((eidx < cnt) ? eidx : 0)];
                float4 pa = *(const float4*)(ev + eidx * 8);      // broadcast
                float4 pb = *(const float4*)(ev + eidx * 8 + 4);
                uint4 u = *(const uint4*)(xbf + (size_t)srcv * 128 + j0);
                a0 = fmaf(__uint_as_float(u.x << 16),          pa.x, a0);
                a1 = fmaf(__uint_as_float(u.x & 0xffff0000u),  pa.y, a1);
                a2 = fmaf(__uint_as_float(u.y << 16),          pa.z, a2);
                a3 = fmaf(__uint_as_float(u.y & 0xffff0000u),  pa.w, a3);
                a4 = fmaf(__uint_as_float(u.z << 16),          pb.x, a4);
                a5 = fmaf(__uint_as_float(u.z & 0xffff0000u),  pb.y, a5);
                a6 = fmaf(__uint_as_float(u.w << 16),          pb.z, a6);
                a7 = fmaf(__uint_as_float(u.w & 0xffff0000u),  pb.w, a7);
            }
        }
        // exp-sum across stripes (keeps head class h = lane&7)
        l += __shfl_xor(l, 8);
        l += __shfl_xor(l, 16);
        l += __shfl_xor(l, 32);
        float invl = (l > 0.f) ? (1.f / l) : 0.f;
        // combine the 4 quarter-wave edge groups
        a0 += __shfl_xor(a0, 16); a0 += __shfl_xor(a0, 32);
        a1 += __shfl_xor(a1, 16); a1 += __shfl_xor(a1, 32);
        a2 += __shfl_xor(a2, 16); a2 += __shfl_xor(a2, 32);
        a3 += __shfl_xor(a3, 16); a3 += __shfl_xor(a3, 32);
        a4 += __shfl_xor(a4, 16); a4 += __shfl_xor(a4, 32);
        a5 += __shfl_xor(a5, 16); a5 += __shfl_xor(a5, 32);
        a6 += __shfl_xor(a6, 16); a6 += __shfl_xor(a6, 32);
        a7 += __shfl_xor(a7, 16); a7 += __shfl_xor(a7, 32);
        float i0 = __shfl(invl, 0), i1 = __shfl(invl, 1);
        float i2 = __shfl(invl, 2), i3 = __shfl(invl, 3);
        float i4v = __shfl(invl, 4), i5 = __shfl(invl, 5);
        float i6 = __shfl(invl, 6), i7 = __shfl(invl, 7);
        if (qtr == 0) {
            float* orow = out + (size_t)n * 384 + 128 + (size_t)t * 128 + j0;
            *(float4*)orow       = make_float4(a0 * i0, a1 * i1, a2 * i2, a3 * i3);
            *(float4*)(orow + 4) = make_float4(a4 * i4v, a5 * i5, a6 * i6, a7 * i7);
        }
    }
}

extern "C" void kernel_launch(void* const* d_in, const int* in_sizes, int n_in,
                              void* d_out, int out_size, void* d_ws, size_t ws_size,
                              hipStream_t stream)
{
    const float* x  = (const float*)d_in[0];
    const float* wu = (const float*)d_in[1];
    const float* bu = (const float*)d_in[2];
    const float* wv = (const float*)d_in[3];
    const int* s0 = (const int*)d_in[4];
    const int* d0 = (const int*)d_in[5];
    const int* s1 = (const int*)d_in[6];
    const int* d1 = (const int*)d_in[7];
    float* out = (float*)d_out;
    int N = in_sizes[0] / 128;
    int E = in_sizes[4];

    int nr = ((N - 1) >> RSHIFT) + 1;               // 782 for N=50000 (<= MAXNR)
    long long mean = (long long)RW * E / N;         // ~1024
    int cap = (int)(mean + mean / 4 + 64);          // 1344 (>9 sigma margin)

    char* ws = (char*)d_ws;
    size_t o = 0;
    auto alloc = [&](size_t bytes) -> void* {
        void* p = ws + o;
        o = (o + bytes + 255) & ~(size_t)255;
        return p;
    };
    float* su       = (float*)alloc((size_t)N * 16 * 4);
    float* sv       = (float*)alloc((size_t)N * 16 * 4);
    int* gcur       = (int*)alloc((size_t)2 * nr * 4);
    unsigned* pairs = (unsigned*)alloc((size_t)2 * nr * cap * 4);
    ushort* xbf     = (ushort*)alloc((size_t)N * 128 * 2);

    int ppset       = (E + CHUNKP - 1) / CHUNKP;    // 98
    int partBlocks  = 2 * ppset;                    // 196
    int scoreBlocks = (N + 63) / 64;                // 782
    int convBlocks  = (N * 32 + 2047) / 2048;       // 782

    hipMemsetAsync(gcur, 0, (size_t)2 * nr * 4, stream);
    mega_kernel<<<partBlocks + scoreBlocks + convBlocks, 256, 0, stream>>>(
        x, wu, bu, wv, s0, d0, s1, d1, out, xbf, su, sv,
        gcur, pairs, N, E, nr, cap, partBlocks, scoreBlocks, ppset);
    buildagg_kernel<<<dim3(nr, 2), 256, 0, stream>>>(
        xbf, su, sv, gcur, pairs, out, N, E, nr, cap);
}